// Round 2
// baseline (292.369 us; speedup 1.0000x reference)
//
#include <hip/hip_runtime.h>

// ============================================================================
// LeViT attention, MI355X. I/O tensors are FLOAT32 (per reference).
// b=2, C=256, H=W=56, n=3136, heads=8, kd=16, dh=64.
// Pipeline: xtw (x->x_t bf16 + W'=s*W bf16) -> qkv (MFMA, no LDS, q scaled by
// log2e; V stored KEY-PERMUTED per 32-group so attn PV frags are contiguous)
// -> attn v12 (flash, NO LDS/barriers: direct L2-resident K/V loads, 1-wave
// blocks, 49 exact chunks) -> proj (MFMA, no LDS, A hoisted).
// ws (u16 elems): qws 802816 | kws 802816 | vws 3211264 | R 3211264
//   (R = x_t during xtw/qkv, o_t from attn on) | wqb 32768 | wkb 32768 |
//   wvb 131072 | wpb 131072   => 16,711,680 B
// MFMA 16x16x32_bf16: A[m=l15][k=quad*8+j]; B[k=quad*8+j][n=l15];
// C/D: col=l15, row=quad*4+reg.
// V permute (qkv write side): within each 32-key group, key a*16+b stored at
// pos (b>>2)*8 + a*4 + (b&3). Read side: lane (quad) loads pos quad*8..+8 ==
// keys (j>>2)*16 + quad*4 + (j&3) -- exactly pf's k-order. 16B contiguous.
// ============================================================================

typedef short  s16x8 __attribute__((ext_vector_type(8)));
typedef float  f32x4 __attribute__((ext_vector_type(4)));
typedef unsigned short u16;
typedef unsigned short u16x4 __attribute__((ext_vector_type(4)));

__device__ __forceinline__ u16 f2bf(float f) {   // RNE
    unsigned u = __builtin_bit_cast(unsigned, f);
    u += 0x7FFF + ((u >> 16) & 1);
    return (u16)(u >> 16);
}
__device__ __forceinline__ u16 f2bf_h(float f) { // round-half-up (cheap, p>0)
    unsigned u = __builtin_bit_cast(unsigned, f);
    return (u16)((u + 0x8000) >> 16);
}
__device__ __forceinline__ f32x4 mfma32(s16x8 a, s16x8 b, f32x4 c) {
    return __builtin_amdgcn_mfma_f32_16x16x32_bf16(a, b, c, 0, 0, 0);
}

// ---------------------------------------------------------------------------
// Fused: z<2 -> x fp32 -> x_t[b][3136][256] bf16 transpose; z==2 -> W'=s*W.
// grid (49,4,3), 256 thr.
// ---------------------------------------------------------------------------
__global__ __launch_bounds__(256) void xtw_kernel(
    const float* __restrict__ x, u16* __restrict__ xt,
    const float* __restrict__ wq, const float* __restrict__ sq,
    const float* __restrict__ wk, const float* __restrict__ sk,
    const float* __restrict__ wv, const float* __restrict__ sv,
    const float* __restrict__ wp, const float* __restrict__ sp,
    u16* __restrict__ wqb, u16* __restrict__ wkb,
    u16* __restrict__ wvb, u16* __restrict__ wpb)
{
    const int t = threadIdx.x;
    if (blockIdx.z == 2) {
        const int base = (blockIdx.y * 49 + blockIdx.x) * 256 + t;
        for (int idx = base; idx < 327680; idx += 50176) {
            if (idx < 32768)        wqb[idx] = f2bf(wq[idx] * sq[idx >> 8]);
            else if (idx < 65536)  { int j = idx - 32768;  wkb[j] = f2bf(wk[j] * sk[j >> 8]); }
            else if (idx < 196608) { int j = idx - 65536;  wvb[j] = f2bf(wv[j] * sv[j >> 8]); }
            else                   { int j = idx - 196608; wpb[j] = f2bf(wp[j] * sp[j >> 9]); }
        }
        return;
    }
    const int b = blockIdx.z, c0 = blockIdx.y * 64, n0 = blockIdx.x * 64;
    __shared__ float lds[64][65];
    const int nl = t & 63, cl = t >> 6;
    #pragma unroll
    for (int i = 0; i < 16; i++) {
        const int c = cl + i * 4;
        lds[c][nl] = x[(b * 256 + c0 + c) * 3136 + n0 + nl];
    }
    __syncthreads();
    #pragma unroll
    for (int i = 0; i < 16; i++) {
        const int n = cl + i * 4;
        xt[(b * 3136 + n0 + n) * 256 + c0 + nl] = f2bf(lds[nl][n]);
    }
}

// ---------------------------------------------------------------------------
// QKV MFMA GEMM, no LDS, A-frags hoisted. grid (49 n-tiles, 12 rt, 2 b).
// rt 0..3: q/k (token-major store; q pre-scaled by log2e); rt 4..11: v
// (stored key-permuted within 32-groups for attn's contiguous PV frags).
// ---------------------------------------------------------------------------
__global__ __launch_bounds__(256, 4) void qkv_kernel(
    const u16* __restrict__ xt,
    const u16* __restrict__ wqb, const u16* __restrict__ wkb, const u16* __restrict__ wvb,
    const float* __restrict__ bq, const float* __restrict__ bk, const float* __restrict__ bv,
    u16* __restrict__ qws, u16* __restrict__ kws, u16* __restrict__ vws)
{
    const int b = blockIdx.z, rt = blockIdx.y, n0 = blockIdx.x * 64;
    const int t = threadIdx.x, wave = t >> 6, lane = t & 63;
    const int l15 = lane & 15, quad = lane >> 4;
    const f32x4 z = {0.f, 0.f, 0.f, 0.f};

    if (rt < 4) {
        const u16* wb      = (rt < 2) ? wqb : wkb;
        const float* bias  = (rt < 2) ? bq : bk;
        u16* dst           = (rt < 2) ? qws : kws;
        const float qs     = (rt < 2) ? 1.44269504088896f : 1.0f;  // fold log2e
        const int och0 = (rt & 1) * 64;
        const int m0   = n0 + wave * 16;
        const u16* xrow = &xt[(b * 3136 + m0 + l15) * 256 + quad * 8];
        s16x8 a8[8];
        #pragma unroll
        for (int kc8 = 0; kc8 < 8; kc8++) a8[kc8] = *(const s16x8*)&xrow[kc8 * 32];
        f32x4 acc[4] = {z, z, z, z};
        #pragma unroll
        for (int kc8 = 0; kc8 < 8; kc8++) {
            #pragma unroll
            for (int f = 0; f < 4; f++) {
                s16x8 bf = *(const s16x8*)&wb[(och0 + f * 16 + l15) * 256 + kc8 * 32 + quad * 8];
                acc[f] = mfma32(a8[kc8], bf, acc[f]);
            }
        }
        #pragma unroll
        for (int f = 0; f < 4; f++) {
            const int och = och0 + f * 16 + l15;
            const float bi = bias[och];
            const int h = och >> 4;
            #pragma unroll
            for (int r = 0; r < 4; r++) {
                const int tok = m0 + quad * 4 + r;
                dst[((b * 8 + h) * 3136 + tok) * 16 + l15] = f2bf((acc[f][r] + bi) * qs);
            }
        }
    } else {
        const int och0 = (rt - 4) * 64 + wave * 16;
        const u16* arow = &wvb[(och0 + l15) * 256 + quad * 8];
        s16x8 a8[8];
        #pragma unroll
        for (int kc8 = 0; kc8 < 8; kc8++) a8[kc8] = *(const s16x8*)&arow[kc8 * 32];
        f32x4 acc[4] = {z, z, z, z};
        #pragma unroll
        for (int kc8 = 0; kc8 < 8; kc8++) {
            #pragma unroll
            for (int f = 0; f < 4; f++) {
                s16x8 bf = *(const s16x8*)&xt[(b * 3136 + n0 + f * 16 + l15) * 256 + kc8 * 32 + quad * 8];
                acc[f] = mfma32(a8[kc8], bf, acc[f]);
            }
        }
        // V write, key-permuted within each 32-token group:
        // token = n0 + f*16 + l15 -> group n0+(f>>1)*32,
        // pos = (l15>>2)*8 + (f&1)*4 + (l15&3)
        #pragma unroll
        for (int r = 0; r < 4; r++) {
            const int och = och0 + quad * 4 + r;
            const float bi = bv[och];
            #pragma unroll
            for (int f = 0; f < 4; f++) {
                const int col = n0 + (f >> 1) * 32 + (l15 >> 2) * 8 + (f & 1) * 4 + (l15 & 3);
                vws[(b * 512 + och) * 3136 + col] = f2bf(acc[f][r] + bi);
            }
        }
    }
}

// ---------------------------------------------------------------------------
// Flash attention v12: NO LDS, NO barriers. K/V are L2-resident per XCD
// (bh%8 swizzle: each XCD touches 2 heads => ~1MB working set in 4MB L2).
// grid (16 bh, 196 q-tiles of 16); 1 wave (64 thr) per block => 3136 blocks,
// tail imbalance ~6% (vs 30% at 784 blocks). 49 exact chunks of 64 keys.
// Per chunk: 4 K-frag loads (coalesced 512B bursts) + 4 QK MFMA -> exp2 pack
// -> 8 V-frag loads (16B contiguous, permuted layout) + 8 PV + 2 rowsum MFMA.
// ---------------------------------------------------------------------------
__global__ __launch_bounds__(64, 4) void attn_kernel(
    const u16* __restrict__ qws, const u16* __restrict__ kws,
    const u16* __restrict__ vws, u16* __restrict__ o_t)
{
    const int bh   = blockIdx.x;                 // x fastest -> XCD = bh%8
    const int nb   = blockIdx.y * 16;            // this wave's query base
    const int lane = threadIdx.x;
    const int l15  = lane & 15, quad = lane >> 4;

    // Q fragment (B-op): B[k=d=quad*8+j][n=query=l15]; zero for d>=16
    s16x8 aq = {0, 0, 0, 0, 0, 0, 0, 0};
    if (quad < 2)
        aq = *(const s16x8*)&qws[(bh * 3136 + nb + l15) * 16 + quad * 8];
    s16x8 ones;
    #pragma unroll
    for (int i = 0; i < 8; i++) ones[i] = (short)0x3F80;   // bf16 1.0

    // K frag base: A[m=key=l15][k=quad*8+j]; quads 2,3 duplicate 0,1 (B=0 there)
    const u16* krow  = &kws[(bh * 3136 + l15) * 16 + (quad & 1) * 8];
    // V frag base: A[m=d=dt*16+l15][k=key]; permuted layout -> 16B contiguous
    const u16* vrow0 = &vws[(bh * 64 + l15) * 3136 + quad * 8];

    f32x4 acc[4], acc5;                          // O^T tiles + rowsum tile
    #pragma unroll
    for (int dt = 0; dt < 4; dt++) acc[dt] = (f32x4){0.f, 0.f, 0.f, 0.f};
    acc5 = (f32x4){0.f, 0.f, 0.f, 0.f};
    const f32x4 z = {0.f, 0.f, 0.f, 0.f};

    for (int c = 0; c < 49; c++) {
        const int kb = c * 64;

        // ---- S^T = K·Q^T : 4 key tiles of 16 (swapped operands)
        f32x4 s[4];
        #pragma unroll
        for (int ii = 0; ii < 4; ii++) {
            s16x8 kf = *(const s16x8*)&krow[(kb + ii * 16) * 16];
            s[ii] = mfma32(kf, aq, z);
        }

        // ---- V fragment loads (independent of scores; issue before exp)
        s16x8 vf[8];
        #pragma unroll
        for (int c32 = 0; c32 < 2; c32++)
            #pragma unroll
            for (int dt = 0; dt < 4; dt++)
                vf[c32 * 4 + dt] =
                    *(const s16x8*)&vrow0[dt * 16 * 3136 + kb + c32 * 32];

        // ---- P pack: pf[c32] = {exp2 s[2c32], exp2 s[2c32+1]}
        s16x8 pf[2];
        #pragma unroll
        for (int c32 = 0; c32 < 2; c32++) {
            #pragma unroll
            for (int r = 0; r < 4; r++) {
                pf[c32][r]     = (short)f2bf_h(__builtin_amdgcn_exp2f(s[2 * c32][r]));
                pf[c32][4 + r] = (short)f2bf_h(__builtin_amdgcn_exp2f(s[2 * c32 + 1][r]));
            }
        }

        // ---- O^T += V^T·P ; rowsum via ones-MFMA
        #pragma unroll
        for (int c32 = 0; c32 < 2; c32++) {
            #pragma unroll
            for (int dt = 0; dt < 4; dt++)
                acc[dt] = mfma32(vf[c32 * 4 + dt], pf[c32], acc[dt]);
            acc5 = mfma32(ones, pf[c32], acc5);
        }
    }

    const float inv = 1.0f / acc5[0];            // rowsum for query l15

    // ---- epilogue: O^T rows d=dt*16+quad*4+r, col l15
    u16* dst = &o_t[(((bh >> 3) * 3136) + nb + l15) * 512 + (bh & 7) * 64];
    #pragma unroll
    for (int dt = 0; dt < 4; dt++) {
        u16x4 o4;
        #pragma unroll
        for (int r = 0; r < 4; r++) o4[r] = f2bf(acc[dt][r] * inv);
        *(u16x4*)&dst[dt * 16 + quad * 4] = o4;
    }
}

// ---------------------------------------------------------------------------
// Output projection MFMA GEMM, no LDS, A hoisted. grid (98, 4, 2).
// A = wp' [256][512], B = o_t [n][512]; C[och][token] -> fp32 out.
// ---------------------------------------------------------------------------
__global__ __launch_bounds__(256, 4) void proj_kernel(
    const u16* __restrict__ o_t, const u16* __restrict__ wpb,
    const float* __restrict__ bp, float* __restrict__ out)
{
    const int b = blockIdx.z, n0 = blockIdx.x * 32;
    const int och0 = blockIdx.y * 64 + (threadIdx.x >> 6) * 16;
    const int lane = threadIdx.x & 63;
    const int l15 = lane & 15, quad = lane >> 4;
    const f32x4 z = {0.f, 0.f, 0.f, 0.f};

    const u16* arow = &wpb[(och0 + l15) * 512 + quad * 8];
    s16x8 a8[16];
    #pragma unroll
    for (int kc = 0; kc < 16; kc++) a8[kc] = *(const s16x8*)&arow[kc * 32];
    f32x4 acc[2] = {z, z};
    #pragma unroll
    for (int kc = 0; kc < 16; kc++) {
        #pragma unroll
        for (int f = 0; f < 2; f++) {
            s16x8 bf = *(const s16x8*)&o_t[(b * 3136 + n0 + f * 16 + l15) * 512 + kc * 32 + quad * 8];
            acc[f] = mfma32(a8[kc], bf, acc[f]);
        }
    }
    #pragma unroll
    for (int r = 0; r < 4; r++) {
        const int och = och0 + quad * 4 + r;
        const float bi = bp[och];
        #pragma unroll
        for (int f = 0; f < 2; f++)
            out[(b * 256 + och) * 3136 + n0 + f * 16 + l15] = acc[f][r] + bi;
    }
}

// ---------------------------------------------------------------------------
extern "C" void kernel_launch(void* const* d_in, const int* in_sizes, int n_in,
                              void* d_out, int out_size, void* d_ws, size_t ws_size,
                              hipStream_t stream) {
    const float* x  = (const float*)d_in[0];
    const float* wq = (const float*)d_in[1];
    const float* sq = (const float*)d_in[2];
    const float* bq = (const float*)d_in[3];
    const float* wk = (const float*)d_in[4];
    const float* sk = (const float*)d_in[5];
    const float* bk = (const float*)d_in[6];
    const float* wv = (const float*)d_in[7];
    const float* sv = (const float*)d_in[8];
    const float* bv = (const float*)d_in[9];
    const float* wp = (const float*)d_in[10];
    const float* sp = (const float*)d_in[11];
    const float* bp = (const float*)d_in[12];
    float* out = (float*)d_out;

    u16* qws = (u16*)d_ws;                 // 802816
    u16* kws = qws + 802816;               // 802816
    u16* vws = kws + 802816;               // 3211264
    u16* R   = vws + 3211264;              // 3211264 (x_t then o_t, overlaid)
    u16* xt  = R;
    u16* ot  = R;
    u16* wqb = R + 3211264;                // 32768
    u16* wkb = wqb + 32768;                // 32768
    u16* wvb = wkb + 32768;                // 131072
    u16* wpb = wvb + 131072;               // 131072  (total 16,711,680 B)

    xtw_kernel<<<dim3(49, 4, 3), 256, 0, stream>>>(x, xt, wq, sq, wk, sk,
                                                   wv, sv, wp, sp,
                                                   wqb, wkb, wvb, wpb);
    qkv_kernel<<<dim3(49, 12, 2), 256, 0, stream>>>(xt, wqb, wkb, wvb,
                                                    bq, bk, bv, qws, kws, vws);
    attn_kernel<<<dim3(16, 196), 64, 0, stream>>>(qws, kws, vws, ot);
    proj_kernel<<<dim3(98, 4, 2), 256, 0, stream>>>(ot, wpb, bp, out);
}

// Round 3
// 182.224 us; speedup vs baseline: 1.6044x; 1.6044x over previous
//
#include <hip/hip_runtime.h>

// ============================================================================
// LeViT attention, MI355X. I/O tensors are FLOAT32 (per reference).
// b=2, C=256, H=W=56, n=3136, heads=8, kd=16, dh=64.
// Pipeline: xtw (x->x_t bf16 + W'=s*W bf16) -> qkv (MFMA, no LDS; V stored
// PACKED in attn fragment order) -> attn v13 (flash, no LDS/barriers,
// fully-coalesced packed-V loads, 2 q-tiles/wave, A/B register double-buffer
// prefetch) -> proj (MFMA, no LDS, A hoisted).
// ws (u16 elems): qws 802816 | kws 802816 | vpk 3211264 | R 3211264
//   (R = x_t during xtw/qkv, o_t from attn on) | wqb 32768 | wkb 32768 |
//   wvb 131072 | wpb 131072   => 16,711,680 B
// MFMA 16x16x32_bf16: A[m=l15][k=quad*8+j]; B[k=quad*8+j][n=l15];
// C/D: col=l15, row=quad*4+reg.
// vpk layout: vpk[((bh*49 + c)*8 + (c32*4+dt))*512 + lane*8 + j] =
//   V[bh][d = dt*16 + (lane&15)][key = c*64 + c32*32 + (j>>2)*16 +
//   (lane>>4)*4 + (j&3)]  -- attn V-frag load = 1024B contiguous per instr.
// Verified: qkv write (c32=f>>1, dt=wave, lane=(l15>>2)*16+quad*4+r,
// j=(f&1)*4+(l15&3)) stores key=c*64+f*16+l15, d=wave*16+quad*4+r.
// ============================================================================

typedef short  s16x8 __attribute__((ext_vector_type(8)));
typedef float  f32x4 __attribute__((ext_vector_type(4)));
typedef unsigned short u16;
typedef unsigned short u16x4 __attribute__((ext_vector_type(4)));

__device__ __forceinline__ u16 f2bf(float f) {   // RNE
    unsigned u = __builtin_bit_cast(unsigned, f);
    u += 0x7FFF + ((u >> 16) & 1);
    return (u16)(u >> 16);
}
__device__ __forceinline__ u16 f2bf_h(float f) { // round-half-up (cheap, p>0)
    unsigned u = __builtin_bit_cast(unsigned, f);
    return (u16)((u + 0x8000) >> 16);
}
__device__ __forceinline__ f32x4 mfma32(s16x8 a, s16x8 b, f32x4 c) {
    return __builtin_amdgcn_mfma_f32_16x16x32_bf16(a, b, c, 0, 0, 0);
}

// ---------------------------------------------------------------------------
// Fused: z<2 -> x fp32 -> x_t[b][3136][256] bf16 transpose; z==2 -> W'=s*W.
// grid (49,4,3), 256 thr.
// ---------------------------------------------------------------------------
__global__ __launch_bounds__(256) void xtw_kernel(
    const float* __restrict__ x, u16* __restrict__ xt,
    const float* __restrict__ wq, const float* __restrict__ sq,
    const float* __restrict__ wk, const float* __restrict__ sk,
    const float* __restrict__ wv, const float* __restrict__ sv,
    const float* __restrict__ wp, const float* __restrict__ sp,
    u16* __restrict__ wqb, u16* __restrict__ wkb,
    u16* __restrict__ wvb, u16* __restrict__ wpb)
{
    const int t = threadIdx.x;
    if (blockIdx.z == 2) {
        const int base = (blockIdx.y * 49 + blockIdx.x) * 256 + t;
        for (int idx = base; idx < 327680; idx += 50176) {
            if (idx < 32768)        wqb[idx] = f2bf(wq[idx] * sq[idx >> 8]);
            else if (idx < 65536)  { int j = idx - 32768;  wkb[j] = f2bf(wk[j] * sk[j >> 8]); }
            else if (idx < 196608) { int j = idx - 65536;  wvb[j] = f2bf(wv[j] * sv[j >> 8]); }
            else                   { int j = idx - 196608; wpb[j] = f2bf(wp[j] * sp[j >> 9]); }
        }
        return;
    }
    const int b = blockIdx.z, c0 = blockIdx.y * 64, n0 = blockIdx.x * 64;
    __shared__ float lds[64][65];
    const int nl = t & 63, cl = t >> 6;
    #pragma unroll
    for (int i = 0; i < 16; i++) {
        const int c = cl + i * 4;
        lds[c][nl] = x[(b * 256 + c0 + c) * 3136 + n0 + nl];
    }
    __syncthreads();
    #pragma unroll
    for (int i = 0; i < 16; i++) {
        const int n = cl + i * 4;
        xt[(b * 3136 + n0 + n) * 256 + c0 + nl] = f2bf(lds[nl][n]);
    }
}

// ---------------------------------------------------------------------------
// QKV MFMA GEMM, no LDS, A-frags hoisted. grid (49 n-tiles, 12 rt, 2 b).
// rt 0..3: q/k (token-major store; q pre-scaled by log2e); rt 4..11: v
// (stored PACKED in attn fragment order, see vpk layout above).
// ---------------------------------------------------------------------------
__global__ __launch_bounds__(256, 4) void qkv_kernel(
    const u16* __restrict__ xt,
    const u16* __restrict__ wqb, const u16* __restrict__ wkb, const u16* __restrict__ wvb,
    const float* __restrict__ bq, const float* __restrict__ bk, const float* __restrict__ bv,
    u16* __restrict__ qws, u16* __restrict__ kws, u16* __restrict__ vpk)
{
    const int b = blockIdx.z, rt = blockIdx.y, n0 = blockIdx.x * 64;
    const int t = threadIdx.x, wave = t >> 6, lane = t & 63;
    const int l15 = lane & 15, quad = lane >> 4;
    const f32x4 z = {0.f, 0.f, 0.f, 0.f};

    if (rt < 4) {
        const u16* wb      = (rt < 2) ? wqb : wkb;
        const float* bias  = (rt < 2) ? bq : bk;
        u16* dst           = (rt < 2) ? qws : kws;
        const float qs     = (rt < 2) ? 1.44269504088896f : 1.0f;  // fold log2e
        const int och0 = (rt & 1) * 64;
        const int m0   = n0 + wave * 16;
        const u16* xrow = &xt[(b * 3136 + m0 + l15) * 256 + quad * 8];
        s16x8 a8[8];
        #pragma unroll
        for (int kc8 = 0; kc8 < 8; kc8++) a8[kc8] = *(const s16x8*)&xrow[kc8 * 32];
        f32x4 acc[4] = {z, z, z, z};
        #pragma unroll
        for (int kc8 = 0; kc8 < 8; kc8++) {
            #pragma unroll
            for (int f = 0; f < 4; f++) {
                s16x8 bf = *(const s16x8*)&wb[(och0 + f * 16 + l15) * 256 + kc8 * 32 + quad * 8];
                acc[f] = mfma32(a8[kc8], bf, acc[f]);
            }
        }
        #pragma unroll
        for (int f = 0; f < 4; f++) {
            const int och = och0 + f * 16 + l15;
            const float bi = bias[och];
            const int h = och >> 4;
            #pragma unroll
            for (int r = 0; r < 4; r++) {
                const int tok = m0 + quad * 4 + r;
                dst[((b * 8 + h) * 3136 + tok) * 16 + l15] = f2bf((acc[f][r] + bi) * qs);
            }
        }
    } else {
        const int h    = rt - 4;
        const int och0 = h * 64 + wave * 16;
        const u16* arow = &wvb[(och0 + l15) * 256 + quad * 8];
        s16x8 a8[8];
        #pragma unroll
        for (int kc8 = 0; kc8 < 8; kc8++) a8[kc8] = *(const s16x8*)&arow[kc8 * 32];
        f32x4 acc[4] = {z, z, z, z};
        #pragma unroll
        for (int kc8 = 0; kc8 < 8; kc8++) {
            #pragma unroll
            for (int f = 0; f < 4; f++) {
                s16x8 bf = *(const s16x8*)&xt[(b * 3136 + n0 + f * 16 + l15) * 256 + kc8 * 32 + quad * 8];
                acc[f] = mfma32(a8[kc8], bf, acc[f]);
            }
        }
        // Packed V write: chunk c = blockIdx.x; dt = wave;
        // value (d = wave*16 + quad*4 + r, key = c*64 + f*16 + l15) goes to
        // block (c32=f>>1, dt=wave), lane=(l15>>2)*16+quad*4+r, j=(f&1)*4+(l15&3)
        u16* vdst = &vpk[(((b * 8 + h) * 49 + blockIdx.x) * 8) * 512];
        #pragma unroll
        for (int r = 0; r < 4; r++) {
            const float bi = bv[och0 + quad * 4 + r];
            const int lane_r8 = ((l15 >> 2) * 16 + quad * 4 + r) * 8;
            #pragma unroll
            for (int f = 0; f < 4; f++) {
                const int idx = ((f >> 1) * 4 + wave) * 512 + lane_r8 + (f & 1) * 4 + (l15 & 3);
                vdst[idx] = f2bf(acc[f][r] + bi);
            }
        }
    }
}

// ---------------------------------------------------------------------------
// Flash attention v13: no LDS/barriers; packed-V -> every V-frag load is a
// single fully-coalesced 1024B instruction; K loads are 512B bursts.
// 2 q-tiles per wave (K/V loads amortized 2x, two independent MFMA chains);
// A/B register double-buffer prefetch of the next 64-key chunk so global
// latency hides under compute. grid (16 bh, 98 q-pairs), 64 thr.
// ---------------------------------------------------------------------------
__global__ __launch_bounds__(64) void attn_kernel(
    const u16* __restrict__ qws, const u16* __restrict__ kws,
    const u16* __restrict__ vpk, u16* __restrict__ o_t)
{
    const int bh   = blockIdx.x;                 // x fastest -> XCD = bh%8
    const int nb   = blockIdx.y * 32;            // 2 q-tiles: nb, nb+16
    const int lane = threadIdx.x;
    const int l15  = lane & 15, quad = lane >> 4;

    // Q fragments (B-op): B[k=d=quad*8+j][n=query=l15]; zero for d>=16
    s16x8 aq[2];
    #pragma unroll
    for (int u = 0; u < 2; u++) {
        aq[u] = (s16x8){0, 0, 0, 0, 0, 0, 0, 0};
        if (quad < 2)
            aq[u] = *(const s16x8*)&qws[(bh * 3136 + nb + u * 16 + l15) * 16 + quad * 8];
    }
    s16x8 ones;
    #pragma unroll
    for (int i = 0; i < 8; i++) ones[i] = (short)0x3F80;   // bf16 1.0

    // K frag base: A[m=key=l15][k=quad*8+j]; quads 2,3 duplicate 0,1 (B=0 there)
    const u16* krow = &kws[(bh * 3136 + l15) * 16 + (quad & 1) * 8];
    // packed V base for this head
    const u16* vb   = &vpk[bh * 49 * 4096 + lane * 8];

    f32x4 acc[2][4], acc5[2];
    #pragma unroll
    for (int u = 0; u < 2; u++) {
        #pragma unroll
        for (int dt = 0; dt < 4; dt++) acc[u][dt] = (f32x4){0.f, 0.f, 0.f, 0.f};
        acc5[u] = (f32x4){0.f, 0.f, 0.f, 0.f};
    }
    const f32x4 z = {0.f, 0.f, 0.f, 0.f};

    s16x8 kfA[4], vfA[8], kfB[4], vfB[8];

    auto loadK = [&](s16x8* kf, int c) {
        #pragma unroll
        for (int ii = 0; ii < 4; ii++)
            kf[ii] = *(const s16x8*)&krow[(c * 64 + ii * 16) * 16];
    };
    auto loadV = [&](s16x8* vf, int c) {
        #pragma unroll
        for (int i = 0; i < 8; i++)
            vf[i] = *(const s16x8*)&vb[(c * 8 + i) * 512];
    };
    auto compute = [&](const s16x8* kf, const s16x8* vf) {
        #pragma unroll
        for (int u = 0; u < 2; u++) {
            // S^T = K·Q^T : 4 key tiles of 16 (swapped operands)
            f32x4 s[4];
            #pragma unroll
            for (int ii = 0; ii < 4; ii++) s[ii] = mfma32(kf[ii], aq[u], z);
            // P pack: pf[c32] = {exp2 s[2c32], exp2 s[2c32+1]}
            s16x8 pf[2];
            #pragma unroll
            for (int c32 = 0; c32 < 2; c32++) {
                #pragma unroll
                for (int r = 0; r < 4; r++) {
                    pf[c32][r]     = (short)f2bf_h(__builtin_amdgcn_exp2f(s[2 * c32][r]));
                    pf[c32][4 + r] = (short)f2bf_h(__builtin_amdgcn_exp2f(s[2 * c32 + 1][r]));
                }
            }
            // O^T += V^T·P ; rowsum via ones-MFMA
            #pragma unroll
            for (int c32 = 0; c32 < 2; c32++) {
                #pragma unroll
                for (int dt = 0; dt < 4; dt++)
                    acc[u][dt] = mfma32(vf[c32 * 4 + dt], pf[c32], acc[u][dt]);
                acc5[u] = mfma32(ones, pf[c32], acc5[u]);
            }
        }
    };

    loadK(kfA, 0); loadV(vfA, 0);
    #pragma unroll 1
    for (int c = 0; c < 49; c += 2) {
        if (c + 1 < 49) { loadK(kfB, c + 1); loadV(vfB, c + 1); }
        compute(kfA, vfA);
        if (c + 2 < 49) { loadK(kfA, c + 2); loadV(vfA, c + 2); }
        if (c + 1 < 49) compute(kfB, vfB);
    }

    // ---- epilogue: O^T rows d=dt*16+quad*4+r, col l15, per q-tile u
    #pragma unroll
    for (int u = 0; u < 2; u++) {
        const float inv = 1.0f / acc5[u][0];     // rowsum for query l15
        u16* dst = &o_t[(((bh >> 3) * 3136) + nb + u * 16 + l15) * 512 + (bh & 7) * 64];
        #pragma unroll
        for (int dt = 0; dt < 4; dt++) {
            u16x4 o4;
            #pragma unroll
            for (int r = 0; r < 4; r++) o4[r] = f2bf(acc[u][dt][r] * inv);
            *(u16x4*)&dst[dt * 16 + quad * 4] = o4;
        }
    }
}

// ---------------------------------------------------------------------------
// Output projection MFMA GEMM, no LDS, A hoisted. grid (98, 4, 2).
// A = wp' [256][512], B = o_t [n][512]; C[och][token] -> fp32 out.
// ---------------------------------------------------------------------------
__global__ __launch_bounds__(256, 4) void proj_kernel(
    const u16* __restrict__ o_t, const u16* __restrict__ wpb,
    const float* __restrict__ bp, float* __restrict__ out)
{
    const int b = blockIdx.z, n0 = blockIdx.x * 32;
    const int och0 = blockIdx.y * 64 + (threadIdx.x >> 6) * 16;
    const int lane = threadIdx.x & 63;
    const int l15 = lane & 15, quad = lane >> 4;
    const f32x4 z = {0.f, 0.f, 0.f, 0.f};

    const u16* arow = &wpb[(och0 + l15) * 512 + quad * 8];
    s16x8 a8[16];
    #pragma unroll
    for (int kc = 0; kc < 16; kc++) a8[kc] = *(const s16x8*)&arow[kc * 32];
    f32x4 acc[2] = {z, z};
    #pragma unroll
    for (int kc = 0; kc < 16; kc++) {
        #pragma unroll
        for (int f = 0; f < 2; f++) {
            s16x8 bf = *(const s16x8*)&o_t[(b * 3136 + n0 + f * 16 + l15) * 512 + kc * 32 + quad * 8];
            acc[f] = mfma32(a8[kc], bf, acc[f]);
        }
    }
    #pragma unroll
    for (int r = 0; r < 4; r++) {
        const int och = och0 + quad * 4 + r;
        const float bi = bp[och];
        #pragma unroll
        for (int f = 0; f < 2; f++)
            out[(b * 256 + och) * 3136 + n0 + f * 16 + l15] = acc[f][r] + bi;
    }
}

// ---------------------------------------------------------------------------
extern "C" void kernel_launch(void* const* d_in, const int* in_sizes, int n_in,
                              void* d_out, int out_size, void* d_ws, size_t ws_size,
                              hipStream_t stream) {
    const float* x  = (const float*)d_in[0];
    const float* wq = (const float*)d_in[1];
    const float* sq = (const float*)d_in[2];
    const float* bq = (const float*)d_in[3];
    const float* wk = (const float*)d_in[4];
    const float* sk = (const float*)d_in[5];
    const float* bk = (const float*)d_in[6];
    const float* wv = (const float*)d_in[7];
    const float* sv = (const float*)d_in[8];
    const float* bv = (const float*)d_in[9];
    const float* wp = (const float*)d_in[10];
    const float* sp = (const float*)d_in[11];
    const float* bp = (const float*)d_in[12];
    float* out = (float*)d_out;

    u16* qws = (u16*)d_ws;                 // 802816
    u16* kws = qws + 802816;               // 802816
    u16* vpk = kws + 802816;               // 3211264 (packed V)
    u16* R   = vpk + 3211264;              // 3211264 (x_t then o_t, overlaid)
    u16* xt  = R;
    u16* ot  = R;
    u16* wqb = R + 3211264;                // 32768
    u16* wkb = wqb + 32768;                // 32768
    u16* wvb = wkb + 32768;                // 131072
    u16* wpb = wvb + 131072;               // 131072  (total 16,711,680 B)

    xtw_kernel<<<dim3(49, 4, 3), 256, 0, stream>>>(x, xt, wq, sq, wk, sk,
                                                   wv, sv, wp, sp,
                                                   wqb, wkb, wvb, wpb);
    qkv_kernel<<<dim3(49, 12, 2), 256, 0, stream>>>(xt, wqb, wkb, wvb,
                                                    bq, bk, bv, qws, kws, vpk);
    attn_kernel<<<dim3(16, 98), 64, 0, stream>>>(qws, kws, vpk, ot);
    proj_kernel<<<dim3(98, 4, 2), 256, 0, stream>>>(ot, wpb, bp, out);
}